// Round 27
// baseline (269.636 us; speedup 1.0000x reference)
//
#include <hip/hip_runtime.h>

#define KC 1024
#define DD 256
#define NROWS 65536
#define BM 128
#define NT 256
#define RESCUE_EPS 0.02f
#define RB 8

typedef _Float16 f16x8 __attribute__((ext_vector_type(8)));
typedef __fp16 fp16x2 __attribute__((ext_vector_type(2)));
typedef float f32x4 __attribute__((ext_vector_type(4)));

__global__ void wprep(const float* __restrict__ W, _Float16* __restrict__ wh,
                      float* __restrict__ se, float4* __restrict__ WT4,
                      float* __restrict__ counts, double* __restrict__ loss,
                      int* __restrict__ flagcnt) {
    int k = blockIdx.x, lane = threadIdx.x;
    float4 v = reinterpret_cast<const float4*>(W + (size_t)k * DD)[lane];
    union { fp16x2 h2[2]; uint2 u; } cv;
    cv.h2[0] = __builtin_amdgcn_cvt_pkrtz(v.x, v.y);
    cv.h2[1] = __builtin_amdgcn_cvt_pkrtz(v.z, v.w);
    *reinterpret_cast<uint2*>(wh + (size_t)k * DD + lane * 4) = cv.u;
    WT4[(size_t)lane * KC + k] = v;
    double s = (double)v.x * v.x + (double)v.y * v.y + (double)v.z * v.z + (double)v.w * v.w;
    for (int m = 32; m >= 1; m >>= 1) s += __shfl_xor(s, m, 64);
    if (lane == 0) {
        se[k] = (float)s;
        counts[k] = 0.0f;
        if (k == 0) { loss[0] = 0.0; flagcnt[0] = 0; }
    }
}

__global__ __launch_bounds__(NT, 2) void vq_mfma(
    const float* __restrict__ X,
    const _Float16* __restrict__ wh,
    const float* __restrict__ se,
    float* __restrict__ out_q, float* __restrict__ out_idx,
    int* __restrict__ idx_int, float* __restrict__ sx_out,
    int* __restrict__ flags, int* __restrict__ count,
    float* __restrict__ counts, double* __restrict__ loss_acc)
{
    __shared__ float sxs[BM];
    __shared__ float ses[KC];
    __shared__ int argidx[BM];
    __shared__ double lred[4];

    const int tid = threadIdx.x;
    const int row0 = blockIdx.x * BM;
    const int w = tid >> 6, lane = tid & 63;   // 4 waves, wave owns rows w*32..w*32+31
    const int m = lane & 15, g = lane >> 4;

    for (int i = tid; i < KC; i += NT) ses[i] = se[i];

    f16x8 ahr[2][8];
#pragma unroll
    for (int rt = 0; rt < 2; ++rt) {
        const float* xr = X + (size_t)(row0 + w * 32 + rt * 16 + m) * DD;
        float p0 = 0.f, p1 = 0.f, p2 = 0.f, p3 = 0.f;
#pragma unroll
        for (int ks = 0; ks < 8; ++ks) {
            float4 a = *reinterpret_cast<const float4*>(xr + ks * 32 + g * 8);
            float4 b = *reinterpret_cast<const float4*>(xr + ks * 32 + g * 8 + 4);
            union { fp16x2 h2[4]; f16x8 h8; } cv;
            cv.h2[0] = __builtin_amdgcn_cvt_pkrtz(a.x, a.y);
            cv.h2[1] = __builtin_amdgcn_cvt_pkrtz(a.z, a.w);
            cv.h2[2] = __builtin_amdgcn_cvt_pkrtz(b.x, b.y);
            cv.h2[3] = __builtin_amdgcn_cvt_pkrtz(b.z, b.w);
            ahr[rt][ks] = cv.h8;
            p0 = fmaf(a.x, a.x, fmaf(b.x, b.x, p0));
            p1 = fmaf(a.y, a.y, fmaf(b.y, b.y, p1));
            p2 = fmaf(a.z, a.z, fmaf(b.z, b.z, p2));
            p3 = fmaf(a.w, a.w, fmaf(b.w, b.w, p3));
        }
        float ss = (p0 + p1) + (p2 + p3);
        ss += __shfl_xor(ss, 16, 64);
        ss += __shfl_xor(ss, 32, 64);
        if (g == 0) sxs[w * 32 + rt * 16 + m] = ss;
    }
    __syncthreads();

    float b1[2][4], b2[2][4];
    int i1[2][4];
#pragma unroll
    for (int rt = 0; rt < 2; ++rt)
#pragma unroll
        for (int j = 0; j < 4; ++j) { b1[rt][j] = 3.4e38f; b2[rt][j] = 3.4e38f; i1[rt][j] = 0; }

    float sxr[2][4];
#pragma unroll
    for (int rt = 0; rt < 2; ++rt)
#pragma unroll
        for (int j = 0; j < 4; ++j) sxr[rt][j] = sxs[w * 32 + rt * 16 + g * 4 + j];

    // B-fragments read DIRECTLY from global (fp16 W = 512 KB, L2/L1-resident).
    // No LDS tile, no staging, no barriers in the K-loop.
    for (int ct = 0; ct < 16; ++ct) {
        const _Float16* wbase = wh + (size_t)ct * 64 * DD;
        f32x4 acc0[4], acc1[4];
#pragma unroll
        for (int cs = 0; cs < 4; ++cs) {
            acc0[cs] = (f32x4){0.f, 0.f, 0.f, 0.f};
            acc1[cs] = (f32x4){0.f, 0.f, 0.f, 0.f};
        }
#pragma unroll
        for (int ks = 0; ks < 8; ++ks) {
            const int kq = ks * 4 + g;
#pragma unroll
            for (int cs = 0; cs < 4; ++cs) {
                const int code = cs * 16 + m;
                f16x8 bh = *reinterpret_cast<const f16x8*>(wbase + code * DD + kq * 8);
                acc0[cs] = __builtin_amdgcn_mfma_f32_16x16x32_f16(ahr[0][ks], bh, acc0[cs], 0, 0, 0);
                acc1[cs] = __builtin_amdgcn_mfma_f32_16x16x32_f16(ahr[1][ks], bh, acc1[cs], 0, 0, 0);
            }
        }
#pragma unroll
        for (int cs = 0; cs < 4; ++cs) {
            const int code = ct * 64 + cs * 16 + m;
            const float sec = ses[code];
#pragma unroll
            for (int rt = 0; rt < 2; ++rt) {
                f32x4 A = rt ? acc1[cs] : acc0[cs];
#pragma unroll
                for (int j = 0; j < 4; ++j) {
                    float s = fmaf(-2.0f, A[j], sxr[rt][j] + sec);
                    if (s < b1[rt][j]) { b2[rt][j] = b1[rt][j]; b1[rt][j] = s; i1[rt][j] = code; }
                    else if (s < b2[rt][j]) { b2[rt][j] = s; }
                }
            }
        }
    }

#pragma unroll
    for (int rt = 0; rt < 2; ++rt)
#pragma unroll
        for (int j = 0; j < 4; ++j) {
            float v1 = b1[rt][j], v2 = b2[rt][j];
            int ix = i1[rt][j];
            for (int mm = 1; mm < 16; mm <<= 1) {
                float ov1 = __shfl_xor(v1, mm, 64);
                int oi = __shfl_xor(ix, mm, 64);
                float ov2 = __shfl_xor(v2, mm, 64);
                float nv2 = fminf(fminf(v2, ov2), fmaxf(v1, ov1));
                if (ov1 < v1 || (ov1 == v1 && oi < ix)) { v1 = ov1; ix = oi; }
                v2 = nv2;
            }
            if (m == 0) {
                int rl = w * 32 + rt * 16 + g * 4 + j;
                argidx[rl] = ix;
                if (v2 - v1 < RESCUE_EPS) {
                    int p = atomicAdd(count, 1);
                    flags[p] = row0 + rl;
                }
            }
        }
    __syncthreads();

    if (tid < BM) {
        int row = row0 + tid;
        int k = argidx[tid];
        idx_int[row] = k;
        out_idx[row] = (float)k;
        sx_out[row] = sxs[tid];
        atomicAdd(&counts[k], 1.0f);
    }

    // register epilogue: out_q = (float)q; fp32 loss
    {
        float lacc = 0.0f;
#pragma unroll
        for (int rt = 0; rt < 2; ++rt) {
            const int rl = w * 32 + rt * 16 + m;
            const int row = row0 + rl;
            const int k = argidx[rl];
            const _Float16* qh = wh + (size_t)k * DD;
            float* orow = out_q + (size_t)row * DD;
#pragma unroll
            for (int ks = 0; ks < 8; ++ks) {
                const int col = ks * 32 + g * 8;
                union { uint4 u; _Float16 h[8]; } qv, xv;
                qv.u = *reinterpret_cast<const uint4*>(qh + col);
                xv.u = *reinterpret_cast<uint4*>(&ahr[rt][ks]);
                float o8[8];
#pragma unroll
                for (int q = 0; q < 8; ++q) {
                    float qf = (float)qv.h[q];
                    float df = qf - (float)xv.h[q];
                    o8[q] = qf;
                    lacc = fmaf(df, df, lacc);
                }
                *reinterpret_cast<float4*>(orow + col)     = *reinterpret_cast<float4*>(&o8[0]);
                *reinterpret_cast<float4*>(orow + col + 4) = *reinterpret_cast<float4*>(&o8[4]);
            }
        }
        for (int mm = 32; mm >= 1; mm >>= 1) lacc += __shfl_xor(lacc, mm, 64);
        if (lane == 0) lred[w] = (double)lacc;
    }
    __syncthreads();
    if (tid == 0) {
        double t = lred[0] + lred[1] + lred[2] + lred[3];
        atomicAdd(loss_acc, t);
    }
}

__global__ __launch_bounds__(256) void rescue(
    const float* __restrict__ X, const float4* __restrict__ WT4,
    const float* __restrict__ Wf,
    const float* __restrict__ se, const float* __restrict__ sx,
    const int* __restrict__ flags, const int* __restrict__ count,
    int* __restrict__ idx_int, float* __restrict__ out_idx,
    float* __restrict__ out_q, float* __restrict__ counts,
    double* __restrict__ loss_acc)
{
    __shared__ __align__(16) float xs[RB][DD];
    __shared__ float rv[RB][256];
    __shared__ int ri[RB][256];
    __shared__ float sxr_s[RB];
    __shared__ int rows_s[RB];
    __shared__ int kn_s[RB], ko_s[RB];
    __shared__ double dred[4];
    const int t = threadIdx.x;
    const int n = count[0];

    for (int base = blockIdx.x * RB; base < n; base += gridDim.x * RB) {
        const int nb = min(RB, n - base);
        for (int idx = t; idx < nb * 64; idx += 256) {
            int r = idx >> 6, c4 = idx & 63;
            float4 v = reinterpret_cast<const float4*>(X + (size_t)flags[base + r] * DD)[c4];
            *reinterpret_cast<float4*>(&xs[r][c4 * 4]) = v;
        }
        if (t < nb) { rows_s[t] = flags[base + t]; sxr_s[t] = sx[flags[base + t]]; }
        __syncthreads();

        float acc[4][RB];
#pragma unroll
        for (int cc = 0; cc < 4; ++cc)
#pragma unroll
            for (int r = 0; r < RB; ++r) acc[cc][r] = 0.0f;

        float4 wv[4], wn[4];
#pragma unroll
        for (int cc = 0; cc < 4; ++cc) wv[cc] = WT4[(size_t)0 * KC + cc * 256 + t];

        for (int d4 = 0; d4 < 64; ++d4) {
            const int dn = (d4 < 63) ? d4 + 1 : 63;
#pragma unroll
            for (int cc = 0; cc < 4; ++cc) wn[cc] = WT4[(size_t)dn * KC + cc * 256 + t];
#pragma unroll
            for (int r = 0; r < RB; ++r) {
                float4 xv = *reinterpret_cast<const float4*>(&xs[r][d4 * 4]);
#pragma unroll
                for (int cc = 0; cc < 4; ++cc)
                    acc[cc][r] = fmaf(xv.w, wv[cc].w, fmaf(xv.z, wv[cc].z,
                                 fmaf(xv.y, wv[cc].y, fmaf(xv.x, wv[cc].x, acc[cc][r]))));
            }
#pragma unroll
            for (int cc = 0; cc < 4; ++cc) wv[cc] = wn[cc];
        }

        float best[RB];
        int bidx[RB];
#pragma unroll
        for (int r = 0; r < RB; ++r) { best[r] = 3.4e38f; bidx[r] = 0; }
#pragma unroll
        for (int cc = 0; cc < 4; ++cc) {
            const int c = cc * 256 + t;
            const float sec = se[c];
#pragma unroll
            for (int r = 0; r < RB; ++r) {
                float s = __fsub_rn(__fadd_rn(sxr_s[r], sec), __fmul_rn(2.0f, acc[cc][r]));
                if (s < best[r] || (s == best[r] && c < bidx[r])) { best[r] = s; bidx[r] = c; }
            }
        }
#pragma unroll
        for (int r = 0; r < RB; ++r) { rv[r][t] = best[r]; ri[r][t] = bidx[r]; }
        __syncthreads();

        for (int sft = 128; sft >= 1; sft >>= 1) {
            if (t < sft) {
#pragma unroll
                for (int r = 0; r < RB; ++r) {
                    float ov = rv[r][t + sft];
                    int oi = ri[r][t + sft];
                    if (ov < rv[r][t] || (ov == rv[r][t] && oi < ri[r][t])) {
                        rv[r][t] = ov; ri[r][t] = oi;
                    }
                }
            }
            __syncthreads();
        }
        if (t < nb) {
            int row = rows_s[t];
            int kn = ri[t][0], ko = idx_int[row];
            kn_s[t] = kn; ko_s[t] = ko;
            if (kn != ko) {
                idx_int[row] = kn;
                out_idx[row] = (float)kn;
                atomicAdd(&counts[ko], -1.0f);
                atomicAdd(&counts[kn], 1.0f);
            }
        }
        __syncthreads();

        for (int r = 0; r < nb; ++r) {
            const int ko = ko_s[r], kn = kn_s[r];
            if (kn != ko) {
                const int row = rows_s[r];
                float x = xs[r][t];
                float qo = Wf[(size_t)ko * DD + t];
                float qn = Wf[(size_t)kn * DD + t];
                float dfn = qn - x, dfo = qo - x;
                out_q[(size_t)row * DD + t] = x + dfn;
                double dl = (double)dfn * dfn - (double)dfo * dfo;
                for (int mm = 32; mm >= 1; mm >>= 1) dl += __shfl_xor(dl, mm, 64);
                if ((t & 63) == 0) dred[t >> 6] = dl;
                __syncthreads();
                if (t == 0) atomicAdd(loss_acc, dred[0] + dred[1] + dred[2] + dred[3]);
                __syncthreads();
            }
        }
        __syncthreads();
    }
}

__global__ void finprefix(const float* __restrict__ ema_cs, float* __restrict__ ncs_buf,
                          const double* __restrict__ loss_acc, float* __restrict__ out_loss,
                          float* __restrict__ n_out, int* __restrict__ off,
                          int* __restrict__ cur)
{
    __shared__ float red[1024];
    __shared__ int s[1024];
    int t = threadIdx.x;
    const float OM = (float)(1.0 - 0.99);
    float cnt = ncs_buf[t];
    s[t] = (int)cnt;
    float ncs = __fadd_rn(__fmul_rn(0.99f, ema_cs[t]), __fmul_rn(OM, cnt));
    ncs_buf[t] = ncs;
    red[t] = ncs;
    __syncthreads();
    for (int st = 512; st >= 1; st >>= 1) {
        if (t < st) red[t] += red[t + st];
        __syncthreads();
    }
    if (t == 0) {
        n_out[0] = red[0];
        float el = (float)(loss_acc[0] / 16777216.0);
        out_loss[0] = __fadd_rn(el, __fmul_rn(0.25f, el));
    }
    for (int d = 1; d < 1024; d <<= 1) {
        int v = (t >= d) ? s[t - d] : 0;
        __syncthreads();
        s[t] += v;
        __syncthreads();
    }
    off[t] = (t == 0) ? 0 : s[t - 1];
    cur[t] = 0;
    if (t == 0) off[1024] = NROWS;
}

__global__ __launch_bounds__(256) void scatter_rows(
    const int* __restrict__ idx_int, const int* __restrict__ off,
    int* __restrict__ cur, int* __restrict__ sorted) {
    int i = blockIdx.x * 256 + threadIdx.x;
    int k = idx_int[i];
    int p = atomicAdd(&cur[k], 1);
    sorted[off[k] + p] = i;
}

__global__ __launch_bounds__(256) void embfin2(
    const float* __restrict__ X, const int* __restrict__ off,
    const int* __restrict__ sorted, const float* __restrict__ ema_avg,
    const float* __restrict__ ncs, const float* __restrict__ n_ptr,
    float* __restrict__ out_avg, float* __restrict__ out_w)
{
    const int k = blockIdx.x, t = threadIdx.x;
    const int s0 = off[k], s1 = off[k + 1];
    float a0 = 0.f, a1 = 0.f, a2 = 0.f, a3 = 0.f;
    int i = s0;
    for (; i + 4 <= s1; i += 4) {
        int r0 = sorted[i], r1 = sorted[i + 1], r2 = sorted[i + 2], r3 = sorted[i + 3];
        a0 += X[(size_t)r0 * DD + t];
        a1 += X[(size_t)r1 * DD + t];
        a2 += X[(size_t)r2 * DD + t];
        a3 += X[(size_t)r3 * DD + t];
    }
    for (; i < s1; ++i) a0 += X[(size_t)sorted[i] * DD + t];
    float total = (a0 + a1) + (a2 + a3);

    const float OM = (float)(1.0 - 0.99);
    const float KEPS = (float)(1024.0 * 1e-5);
    size_t o = (size_t)k * DD + t;
    float avg = __fadd_rn(__fmul_rn(0.99f, ema_avg[o]), __fmul_rn(OM, total));
    float n = n_ptr[0];
    float cs = __fmul_rn(__fdiv_rn(__fadd_rn(ncs[k], 1e-5f), __fadd_rn(n, KEPS)), n);
    out_avg[o] = avg;
    out_w[o] = __fdiv_rn(avg, cs);
}

extern "C" void kernel_launch(void* const* d_in, const int* in_sizes, int n_in,
                              void* d_out, int out_size, void* d_ws, size_t ws_size,
                              hipStream_t stream) {
    const float* X = (const float*)d_in[0];
    const float* W = (const float*)d_in[1];
    const float* ema_cs = (const float*)d_in[2];
    const float* ema_avg = (const float*)d_in[3];

    float* out = (float*)d_out;
    float* out_q    = out;
    float* out_loss = out + 16777216;
    float* out_idx  = out + 16777217;
    float* out_w    = out + 16842753;
    float* out_ncs  = out + 17104897;
    float* out_avg  = out + 17105921;

    char* ws = (char*)d_ws;
    float* se      = (float*)(ws + 0);
    float* n_ptr   = (float*)(ws + 4096);
    double* loss   = (double*)(ws + 4112);
    int*   count   = (int*)(ws + 4128);
    _Float16* wh   = (_Float16*)(ws + 8192);
    float* sx      = (float*)(ws + 1056768);
    int*   idx_int = (int*)(ws + 1318912);
    int*   flags   = (int*)(ws + 1581056);
    float4* WT4    = (float4*)(ws + 2097152);
    int*   off     = (int*)(ws + 3145728);
    int*   cur     = (int*)(ws + 3153920);
    int*   sorted  = (int*)(ws + 3158016);

    wprep<<<KC, 64, 0, stream>>>(W, wh, se, WT4, out_ncs, loss, count);
    vq_mfma<<<NROWS / BM, NT, 0, stream>>>(X, wh, se, out_q, out_idx,
                                           idx_int, sx, flags, count,
                                           out_ncs, loss);
    rescue<<<512, 256, 0, stream>>>(X, WT4, W, se, sx, flags, count, idx_int, out_idx,
                                    out_q, out_ncs, loss);
    finprefix<<<1, 1024, 0, stream>>>(ema_cs, out_ncs, loss, out_loss, n_ptr, off, cur);
    scatter_rows<<<NROWS / 256, 256, 0, stream>>>(idx_int, off, cur, sorted);
    embfin2<<<KC, 256, 0, stream>>>(X, off, sorted, ema_avg, out_ncs, n_ptr,
                                    out_avg, out_w);
}

// Round 28
// 193.550 us; speedup vs baseline: 1.3931x; 1.3931x over previous
//
#include <hip/hip_runtime.h>

#define KC 1024
#define DD 256
#define NROWS 65536
#define BM 128
#define NT 256
#define RESCUE_EPS 0.02f
#define RB 8

typedef _Float16 f16x8 __attribute__((ext_vector_type(8)));
typedef __fp16 fp16x2 __attribute__((ext_vector_type(2)));
typedef float f32x4 __attribute__((ext_vector_type(4)));
typedef const __attribute__((address_space(1))) unsigned int* gptr_t;
typedef __attribute__((address_space(3))) unsigned int* lptr_t;

__global__ void wprep(const float* __restrict__ W, _Float16* __restrict__ wh,
                      float* __restrict__ se, float4* __restrict__ WT4,
                      float* __restrict__ counts, double* __restrict__ loss,
                      int* __restrict__ flagcnt) {
    int k = blockIdx.x, lane = threadIdx.x;
    float4 v = reinterpret_cast<const float4*>(W + (size_t)k * DD)[lane];
    union { fp16x2 h2[2]; uint2 u; } cv;
    cv.h2[0] = __builtin_amdgcn_cvt_pkrtz(v.x, v.y);
    cv.h2[1] = __builtin_amdgcn_cvt_pkrtz(v.z, v.w);
    *reinterpret_cast<uint2*>(wh + (size_t)k * DD + lane * 4) = cv.u;
    WT4[(size_t)lane * KC + k] = v;
    double s = (double)v.x * v.x + (double)v.y * v.y + (double)v.z * v.z + (double)v.w * v.w;
    for (int m = 32; m >= 1; m >>= 1) s += __shfl_xor(s, m, 64);
    if (lane == 0) {
        se[k] = (float)s;
        counts[k] = 0.0f;
        if (k == 0) { loss[0] = 0.0; flagcnt[0] = 0; }
    }
}

__global__ __launch_bounds__(NT, 2) void vq_mfma(
    const float* __restrict__ X,
    const _Float16* __restrict__ wh,
    const float* __restrict__ se,
    float* __restrict__ out_q, float* __restrict__ out_idx,
    int* __restrict__ idx_int, float* __restrict__ sx_out,
    int* __restrict__ flags, int* __restrict__ count,
    float* __restrict__ counts, double* __restrict__ loss_acc)
{
    // wave-private double-buffered 16-code tiles: [wave][buf][16*256]
    __shared__ __align__(16) _Float16 wt[4][2][16 * 256];  // 64 KB
    __shared__ float sxs[BM];
    __shared__ float ses[KC];
    __shared__ int argidx[BM];
    __shared__ double lred[4];

    const int tid = threadIdx.x;
    const int row0 = blockIdx.x * BM;
    const int w = tid >> 6, lane = tid & 63;   // 4 waves, wave owns rows w*32..w*32+31
    const int m = lane & 15, g = lane >> 4;

    for (int i = tid; i < KC; i += NT) ses[i] = se[i];

    f16x8 ahr[2][8];
#pragma unroll
    for (int rt = 0; rt < 2; ++rt) {
        const float* xr = X + (size_t)(row0 + w * 32 + rt * 16 + m) * DD;
        float p0 = 0.f, p1 = 0.f, p2 = 0.f, p3 = 0.f;
#pragma unroll
        for (int ks = 0; ks < 8; ++ks) {
            float4 a = *reinterpret_cast<const float4*>(xr + ks * 32 + g * 8);
            float4 b = *reinterpret_cast<const float4*>(xr + ks * 32 + g * 8 + 4);
            union { fp16x2 h2[4]; f16x8 h8; } cv;
            cv.h2[0] = __builtin_amdgcn_cvt_pkrtz(a.x, a.y);
            cv.h2[1] = __builtin_amdgcn_cvt_pkrtz(a.z, a.w);
            cv.h2[2] = __builtin_amdgcn_cvt_pkrtz(b.x, b.y);
            cv.h2[3] = __builtin_amdgcn_cvt_pkrtz(b.z, b.w);
            ahr[rt][ks] = cv.h8;
            p0 = fmaf(a.x, a.x, fmaf(b.x, b.x, p0));
            p1 = fmaf(a.y, a.y, fmaf(b.y, b.y, p1));
            p2 = fmaf(a.z, a.z, fmaf(b.z, b.z, p2));
            p3 = fmaf(a.w, a.w, fmaf(b.w, b.w, p3));
        }
        float ss = (p0 + p1) + (p2 + p3);
        ss += __shfl_xor(ss, 16, 64);
        ss += __shfl_xor(ss, 32, 64);
        if (g == 0) sxs[w * 32 + rt * 16 + m] = ss;
    }
    __syncthreads();

    float sxr[2][4];
#pragma unroll
    for (int rt = 0; rt < 2; ++rt)
#pragma unroll
        for (int j = 0; j < 4; ++j) sxr[rt][j] = sxs[w * 32 + rt * 16 + g * 4 + j];

    // per-lane constant offsets: 512 granules/tile, 8 per lane
    unsigned srcoff[8], ldsoff[8];
#pragma unroll
    for (int p = 0; p < 8; ++p) {
        int gi = p * 64 + lane;
        int code = gi >> 5, j = gi & 31;
        int kq = j ^ code;                      // code in 0..15
        srcoff[p] = (unsigned)(code * DD + kq * 8);
        ldsoff[p] = gi * 8;
    }
    auto stage = [&](int ct, int buf) {
        const _Float16* b = wh + (size_t)ct * 16 * DD;
#pragma unroll
        for (int p = 0; p < 8; ++p)
            __builtin_amdgcn_global_load_lds((gptr_t)(const void*)(b + srcoff[p]),
                                             (lptr_t)(void*)&wt[w][buf][ldsoff[p]], 16, 0, 0);
    };

    float b1[2][4], b2[2][4];
    int i1[2][4];
#pragma unroll
    for (int rt = 0; rt < 2; ++rt)
#pragma unroll
        for (int j = 0; j < 4; ++j) { b1[rt][j] = 3.4e38f; b2[rt][j] = 3.4e38f; i1[rt][j] = 0; }

    stage(0, 0);
    int buf = 0;
    // barrier-free K-loop: wave-private tiles + counted vmcnt (prefetch stays in flight)
    for (int ct = 0; ct < 64; ++ct) {
        if (ct < 63) {
            asm volatile("s_waitcnt lgkmcnt(0)" ::: "memory");  // prior reads of buf^1 done
            stage(ct + 1, buf ^ 1);
            asm volatile("s_waitcnt vmcnt(8)" ::: "memory");    // tile ct landed; ct+1 in flight
        } else {
            asm volatile("s_waitcnt vmcnt(0)" ::: "memory");
        }
        __builtin_amdgcn_sched_barrier(0);

        const _Float16* wtb = wt[w][buf];
        f32x4 acc0 = {0.f, 0.f, 0.f, 0.f}, acc1 = {0.f, 0.f, 0.f, 0.f};
#pragma unroll
        for (int ks = 0; ks < 8; ++ks) {
            const int kq = ks * 4 + g;
            const int L = m * 32 + (kq ^ m);
            f16x8 bh = *reinterpret_cast<const f16x8*>(wtb + L * 8);
            acc0 = __builtin_amdgcn_mfma_f32_16x16x32_f16(ahr[0][ks], bh, acc0, 0, 0, 0);
            acc1 = __builtin_amdgcn_mfma_f32_16x16x32_f16(ahr[1][ks], bh, acc1, 0, 0, 0);
        }
        const int code = ct * 16 + m;
        const float sec = ses[code];
#pragma unroll
        for (int rt = 0; rt < 2; ++rt) {
            f32x4 A = rt ? acc1 : acc0;
#pragma unroll
            for (int j = 0; j < 4; ++j) {
                float s = fmaf(-2.0f, A[j], sxr[rt][j] + sec);
                if (s < b1[rt][j]) { b2[rt][j] = b1[rt][j]; b1[rt][j] = s; i1[rt][j] = code; }
                else if (s < b2[rt][j]) { b2[rt][j] = s; }
            }
        }
        buf ^= 1;
    }

#pragma unroll
    for (int rt = 0; rt < 2; ++rt)
#pragma unroll
        for (int j = 0; j < 4; ++j) {
            float v1 = b1[rt][j], v2 = b2[rt][j];
            int ix = i1[rt][j];
            for (int mm = 1; mm < 16; mm <<= 1) {
                float ov1 = __shfl_xor(v1, mm, 64);
                int oi = __shfl_xor(ix, mm, 64);
                float ov2 = __shfl_xor(v2, mm, 64);
                float nv2 = fminf(fminf(v2, ov2), fmaxf(v1, ov1));
                if (ov1 < v1 || (ov1 == v1 && oi < ix)) { v1 = ov1; ix = oi; }
                v2 = nv2;
            }
            if (m == 0) {
                int rl = w * 32 + rt * 16 + g * 4 + j;
                argidx[rl] = ix;
                if (v2 - v1 < RESCUE_EPS) {
                    int p = atomicAdd(count, 1);
                    flags[p] = row0 + rl;
                }
            }
        }
    __syncthreads();

    if (tid < BM) {
        int row = row0 + tid;
        int k = argidx[tid];
        idx_int[row] = k;
        out_idx[row] = (float)k;
        sx_out[row] = sxs[tid];
        atomicAdd(&counts[k], 1.0f);
    }

    // register epilogue: out_q = (float)q; fp32 loss
    {
        float lacc = 0.0f;
#pragma unroll
        for (int rt = 0; rt < 2; ++rt) {
            const int rl = w * 32 + rt * 16 + m;
            const int row = row0 + rl;
            const int k = argidx[rl];
            const _Float16* qh = wh + (size_t)k * DD;
            float* orow = out_q + (size_t)row * DD;
#pragma unroll
            for (int ks = 0; ks < 8; ++ks) {
                const int col = ks * 32 + g * 8;
                union { uint4 u; _Float16 h[8]; } qv, xv;
                qv.u = *reinterpret_cast<const uint4*>(qh + col);
                xv.u = *reinterpret_cast<uint4*>(&ahr[rt][ks]);
                float o8[8];
#pragma unroll
                for (int q = 0; q < 8; ++q) {
                    float qf = (float)qv.h[q];
                    float df = qf - (float)xv.h[q];
                    o8[q] = qf;
                    lacc = fmaf(df, df, lacc);
                }
                *reinterpret_cast<float4*>(orow + col)     = *reinterpret_cast<float4*>(&o8[0]);
                *reinterpret_cast<float4*>(orow + col + 4) = *reinterpret_cast<float4*>(&o8[4]);
            }
        }
        for (int mm = 32; mm >= 1; mm >>= 1) lacc += __shfl_xor(lacc, mm, 64);
        if (lane == 0) lred[w] = (double)lacc;
    }
    __syncthreads();
    if (tid == 0) {
        double t = lred[0] + lred[1] + lred[2] + lred[3];
        atomicAdd(loss_acc, t);
    }
}

__global__ __launch_bounds__(256) void rescue(
    const float* __restrict__ X, const float4* __restrict__ WT4,
    const float* __restrict__ Wf,
    const float* __restrict__ se, const float* __restrict__ sx,
    const int* __restrict__ flags, const int* __restrict__ count,
    int* __restrict__ idx_int, float* __restrict__ out_idx,
    float* __restrict__ out_q, float* __restrict__ counts,
    double* __restrict__ loss_acc)
{
    __shared__ __align__(16) float xs[RB][DD];
    __shared__ float rv[RB][256];
    __shared__ int ri[RB][256];
    __shared__ float sxr_s[RB];
    __shared__ int rows_s[RB];
    __shared__ int kn_s[RB], ko_s[RB];
    __shared__ double dred[4];
    const int t = threadIdx.x;
    const int n = count[0];

    for (int base = blockIdx.x * RB; base < n; base += gridDim.x * RB) {
        const int nb = min(RB, n - base);
        for (int idx = t; idx < nb * 64; idx += 256) {
            int r = idx >> 6, c4 = idx & 63;
            float4 v = reinterpret_cast<const float4*>(X + (size_t)flags[base + r] * DD)[c4];
            *reinterpret_cast<float4*>(&xs[r][c4 * 4]) = v;
        }
        if (t < nb) { rows_s[t] = flags[base + t]; sxr_s[t] = sx[flags[base + t]]; }
        __syncthreads();

        float acc[4][RB];
#pragma unroll
        for (int cc = 0; cc < 4; ++cc)
#pragma unroll
            for (int r = 0; r < RB; ++r) acc[cc][r] = 0.0f;

        float4 wv[4], wn[4];
#pragma unroll
        for (int cc = 0; cc < 4; ++cc) wv[cc] = WT4[(size_t)0 * KC + cc * 256 + t];

        for (int d4 = 0; d4 < 64; ++d4) {
            const int dn = (d4 < 63) ? d4 + 1 : 63;
#pragma unroll
            for (int cc = 0; cc < 4; ++cc) wn[cc] = WT4[(size_t)dn * KC + cc * 256 + t];
#pragma unroll
            for (int r = 0; r < RB; ++r) {
                float4 xv = *reinterpret_cast<const float4*>(&xs[r][d4 * 4]);
#pragma unroll
                for (int cc = 0; cc < 4; ++cc)
                    acc[cc][r] = fmaf(xv.w, wv[cc].w, fmaf(xv.z, wv[cc].z,
                                 fmaf(xv.y, wv[cc].y, fmaf(xv.x, wv[cc].x, acc[cc][r]))));
            }
#pragma unroll
            for (int cc = 0; cc < 4; ++cc) wv[cc] = wn[cc];
        }

        float best[RB];
        int bidx[RB];
#pragma unroll
        for (int r = 0; r < RB; ++r) { best[r] = 3.4e38f; bidx[r] = 0; }
#pragma unroll
        for (int cc = 0; cc < 4; ++cc) {
            const int c = cc * 256 + t;
            const float sec = se[c];
#pragma unroll
            for (int r = 0; r < RB; ++r) {
                float s = __fsub_rn(__fadd_rn(sxr_s[r], sec), __fmul_rn(2.0f, acc[cc][r]));
                if (s < best[r] || (s == best[r] && c < bidx[r])) { best[r] = s; bidx[r] = c; }
            }
        }
#pragma unroll
        for (int r = 0; r < RB; ++r) { rv[r][t] = best[r]; ri[r][t] = bidx[r]; }
        __syncthreads();

        for (int sft = 128; sft >= 1; sft >>= 1) {
            if (t < sft) {
#pragma unroll
                for (int r = 0; r < RB; ++r) {
                    float ov = rv[r][t + sft];
                    int oi = ri[r][t + sft];
                    if (ov < rv[r][t] || (ov == rv[r][t] && oi < ri[r][t])) {
                        rv[r][t] = ov; ri[r][t] = oi;
                    }
                }
            }
            __syncthreads();
        }
        if (t < nb) {
            int row = rows_s[t];
            int kn = ri[t][0], ko = idx_int[row];
            kn_s[t] = kn; ko_s[t] = ko;
            if (kn != ko) {
                idx_int[row] = kn;
                out_idx[row] = (float)kn;
                atomicAdd(&counts[ko], -1.0f);
                atomicAdd(&counts[kn], 1.0f);
            }
        }
        __syncthreads();

        for (int r = 0; r < nb; ++r) {
            const int ko = ko_s[r], kn = kn_s[r];
            if (kn != ko) {
                const int row = rows_s[r];
                float x = xs[r][t];
                float qo = Wf[(size_t)ko * DD + t];
                float qn = Wf[(size_t)kn * DD + t];
                float dfn = qn - x, dfo = qo - x;
                out_q[(size_t)row * DD + t] = x + dfn;
                double dl = (double)dfn * dfn - (double)dfo * dfo;
                for (int mm = 32; mm >= 1; mm >>= 1) dl += __shfl_xor(dl, mm, 64);
                if ((t & 63) == 0) dred[t >> 6] = dl;
                __syncthreads();
                if (t == 0) atomicAdd(loss_acc, dred[0] + dred[1] + dred[2] + dred[3]);
                __syncthreads();
            }
        }
        __syncthreads();
    }
}

__global__ void finprefix(const float* __restrict__ ema_cs, float* __restrict__ ncs_buf,
                          const double* __restrict__ loss_acc, float* __restrict__ out_loss,
                          float* __restrict__ n_out, int* __restrict__ off,
                          int* __restrict__ cur)
{
    __shared__ float red[1024];
    __shared__ int s[1024];
    int t = threadIdx.x;
    const float OM = (float)(1.0 - 0.99);
    float cnt = ncs_buf[t];
    s[t] = (int)cnt;
    float ncs = __fadd_rn(__fmul_rn(0.99f, ema_cs[t]), __fmul_rn(OM, cnt));
    ncs_buf[t] = ncs;
    red[t] = ncs;
    __syncthreads();
    for (int st = 512; st >= 1; st >>= 1) {
        if (t < st) red[t] += red[t + st];
        __syncthreads();
    }
    if (t == 0) {
        n_out[0] = red[0];
        float el = (float)(loss_acc[0] / 16777216.0);
        out_loss[0] = __fadd_rn(el, __fmul_rn(0.25f, el));
    }
    for (int d = 1; d < 1024; d <<= 1) {
        int v = (t >= d) ? s[t - d] : 0;
        __syncthreads();
        s[t] += v;
        __syncthreads();
    }
    off[t] = (t == 0) ? 0 : s[t - 1];
    cur[t] = 0;
    if (t == 0) off[1024] = NROWS;
}

__global__ __launch_bounds__(256) void scatter_rows(
    const int* __restrict__ idx_int, const int* __restrict__ off,
    int* __restrict__ cur, int* __restrict__ sorted) {
    int i = blockIdx.x * 256 + threadIdx.x;
    int k = idx_int[i];
    int p = atomicAdd(&cur[k], 1);
    sorted[off[k] + p] = i;
}

__global__ __launch_bounds__(256) void embfin2(
    const float* __restrict__ X, const int* __restrict__ off,
    const int* __restrict__ sorted, const float* __restrict__ ema_avg,
    const float* __restrict__ ncs, const float* __restrict__ n_ptr,
    float* __restrict__ out_avg, float* __restrict__ out_w)
{
    const int k = blockIdx.x, t = threadIdx.x;
    const int s0 = off[k], s1 = off[k + 1];
    float a0 = 0.f, a1 = 0.f, a2 = 0.f, a3 = 0.f;
    int i = s0;
    for (; i + 4 <= s1; i += 4) {
        int r0 = sorted[i], r1 = sorted[i + 1], r2 = sorted[i + 2], r3 = sorted[i + 3];
        a0 += X[(size_t)r0 * DD + t];
        a1 += X[(size_t)r1 * DD + t];
        a2 += X[(size_t)r2 * DD + t];
        a3 += X[(size_t)r3 * DD + t];
    }
    for (; i < s1; ++i) a0 += X[(size_t)sorted[i] * DD + t];
    float total = (a0 + a1) + (a2 + a3);

    const float OM = (float)(1.0 - 0.99);
    const float KEPS = (float)(1024.0 * 1e-5);
    size_t o = (size_t)k * DD + t;
    float avg = __fadd_rn(__fmul_rn(0.99f, ema_avg[o]), __fmul_rn(OM, total));
    float n = n_ptr[0];
    float cs = __fmul_rn(__fdiv_rn(__fadd_rn(ncs[k], 1e-5f), __fadd_rn(n, KEPS)), n);
    out_avg[o] = avg;
    out_w[o] = __fdiv_rn(avg, cs);
}

extern "C" void kernel_launch(void* const* d_in, const int* in_sizes, int n_in,
                              void* d_out, int out_size, void* d_ws, size_t ws_size,
                              hipStream_t stream) {
    const float* X = (const float*)d_in[0];
    const float* W = (const float*)d_in[1];
    const float* ema_cs = (const float*)d_in[2];
    const float* ema_avg = (const float*)d_in[3];

    float* out = (float*)d_out;
    float* out_q    = out;
    float* out_loss = out + 16777216;
    float* out_idx  = out + 16777217;
    float* out_w    = out + 16842753;
    float* out_ncs  = out + 17104897;
    float* out_avg  = out + 17105921;

    char* ws = (char*)d_ws;
    float* se      = (float*)(ws + 0);
    float* n_ptr   = (float*)(ws + 4096);
    double* loss   = (double*)(ws + 4112);
    int*   count   = (int*)(ws + 4128);
    _Float16* wh   = (_Float16*)(ws + 8192);
    float* sx      = (float*)(ws + 1056768);
    int*   idx_int = (int*)(ws + 1318912);
    int*   flags   = (int*)(ws + 1581056);
    float4* WT4    = (float4*)(ws + 2097152);
    int*   off     = (int*)(ws + 3145728);
    int*   cur     = (int*)(ws + 3153920);
    int*   sorted  = (int*)(ws + 3158016);

    wprep<<<KC, 64, 0, stream>>>(W, wh, se, WT4, out_ncs, loss, count);
    vq_mfma<<<NROWS / BM, NT, 0, stream>>>(X, wh, se, out_q, out_idx,
                                           idx_int, sx, flags, count,
                                           out_ncs, loss);
    rescue<<<512, 256, 0, stream>>>(X, WT4, W, se, sx, flags, count, idx_int, out_idx,
                                    out_q, out_ncs, loss);
    finprefix<<<1, 1024, 0, stream>>>(ema_cs, out_ncs, loss, out_loss, n_ptr, off, cur);
    scatter_rows<<<NROWS / 256, 256, 0, stream>>>(idx_int, off, cur, sorted);
    embfin2<<<KC, 256, 0, stream>>>(X, off, sorted, ema_avg, out_ncs, n_ptr,
                                    out_avg, out_w);
}

// Round 29
// 176.492 us; speedup vs baseline: 1.5278x; 1.0967x over previous
//
#include <hip/hip_runtime.h>

#define KC 1024
#define DD 256
#define NROWS 65536
#define BM 128
#define NT 256
#define RESCUE_EPS 0.02f
#define RB 8

typedef _Float16 f16x8 __attribute__((ext_vector_type(8)));
typedef __fp16 fp16x2 __attribute__((ext_vector_type(2)));
typedef float f32x4 __attribute__((ext_vector_type(4)));
typedef const __attribute__((address_space(1))) unsigned int* gptr_t;
typedef __attribute__((address_space(3))) unsigned int* lptr_t;

__global__ void wprep(const float* __restrict__ W, _Float16* __restrict__ wh,
                      float* __restrict__ se, float4* __restrict__ WT4,
                      float* __restrict__ counts, double* __restrict__ loss,
                      int* __restrict__ flagcnt) {
    int k = blockIdx.x, lane = threadIdx.x;
    float4 v = reinterpret_cast<const float4*>(W + (size_t)k * DD)[lane];
    union { fp16x2 h2[2]; uint2 u; } cv;
    cv.h2[0] = __builtin_amdgcn_cvt_pkrtz(v.x, v.y);
    cv.h2[1] = __builtin_amdgcn_cvt_pkrtz(v.z, v.w);
    *reinterpret_cast<uint2*>(wh + (size_t)k * DD + lane * 4) = cv.u;
    WT4[(size_t)lane * KC + k] = v;
    double s = (double)v.x * v.x + (double)v.y * v.y + (double)v.z * v.z + (double)v.w * v.w;
    for (int m = 32; m >= 1; m >>= 1) s += __shfl_xor(s, m, 64);
    if (lane == 0) {
        se[k] = (float)s;
        counts[k] = 0.0f;
        if (k == 0) { loss[0] = 0.0; flagcnt[0] = 0; }
    }
}

__global__ __launch_bounds__(NT, 2) void vq_mfma(
    const float* __restrict__ X,
    const _Float16* __restrict__ wh,
    const float* __restrict__ se,
    float* __restrict__ out_q, float* __restrict__ out_idx,
    int* __restrict__ idx_int, float* __restrict__ sx_out,
    int* __restrict__ flags, int* __restrict__ count,
    float* __restrict__ counts, double* __restrict__ loss_acc)
{
    __shared__ __align__(16) _Float16 wt[2][64 * 256];  // 32 KB x2
    __shared__ float sxs[BM];
    __shared__ float ses[KC];
    __shared__ int argidx[BM];
    __shared__ double lred[4];

    const int tid = threadIdx.x;
    const int row0 = blockIdx.x * BM;
    const int w = tid >> 6, lane = tid & 63;   // 4 waves, wave owns rows w*32..w*32+31
    const int m = lane & 15, g = lane >> 4;

    for (int i = tid; i < KC; i += NT) ses[i] = se[i];

    f16x8 ahr[2][8];
#pragma unroll
    for (int rt = 0; rt < 2; ++rt) {
        const float* xr = X + (size_t)(row0 + w * 32 + rt * 16 + m) * DD;
        float p0 = 0.f, p1 = 0.f, p2 = 0.f, p3 = 0.f;
#pragma unroll
        for (int ks = 0; ks < 8; ++ks) {
            float4 a = *reinterpret_cast<const float4*>(xr + ks * 32 + g * 8);
            float4 b = *reinterpret_cast<const float4*>(xr + ks * 32 + g * 8 + 4);
            union { fp16x2 h2[4]; f16x8 h8; } cv;
            cv.h2[0] = __builtin_amdgcn_cvt_pkrtz(a.x, a.y);
            cv.h2[1] = __builtin_amdgcn_cvt_pkrtz(a.z, a.w);
            cv.h2[2] = __builtin_amdgcn_cvt_pkrtz(b.x, b.y);
            cv.h2[3] = __builtin_amdgcn_cvt_pkrtz(b.z, b.w);
            ahr[rt][ks] = cv.h8;
            p0 = fmaf(a.x, a.x, fmaf(b.x, b.x, p0));
            p1 = fmaf(a.y, a.y, fmaf(b.y, b.y, p1));
            p2 = fmaf(a.z, a.z, fmaf(b.z, b.z, p2));
            p3 = fmaf(a.w, a.w, fmaf(b.w, b.w, p3));
        }
        float ss = (p0 + p1) + (p2 + p3);
        ss += __shfl_xor(ss, 16, 64);
        ss += __shfl_xor(ss, 32, 64);
        if (g == 0) sxs[w * 32 + rt * 16 + m] = ss;
    }
    __syncthreads();

    float sxr[2][4];
#pragma unroll
    for (int rt = 0; rt < 2; ++rt)
#pragma unroll
        for (int j = 0; j < 4; ++j) sxr[rt][j] = sxs[w * 32 + rt * 16 + g * 4 + j];

    // 8 granules per thread (2048 granules / 256 threads); 64-code tile, XOR-swizzled source
    unsigned srcoff[8], ldsoff[8];
#pragma unroll
    for (int p = 0; p < 8; ++p) {
        int gi = p * NT + tid;
        int code = gi >> 5, j = gi & 31;
        int kq = j ^ (code & 31);
        srcoff[p] = (unsigned)(code * DD + kq * 8);
        ldsoff[p] = gi * 8;
    }
    auto stage = [&](int ct, int buf) {
        const _Float16* b = wh + (size_t)ct * 64 * DD;
#pragma unroll
        for (int p = 0; p < 8; ++p)
            __builtin_amdgcn_global_load_lds((gptr_t)(const void*)(b + srcoff[p]),
                                             (lptr_t)(void*)&wt[buf][ldsoff[p]], 16, 0, 0);
    };

    float b1[2][4], b2[2][4];
    int i1[2][4];
#pragma unroll
    for (int rt = 0; rt < 2; ++rt)
#pragma unroll
        for (int j = 0; j < 4; ++j) { b1[rt][j] = 3.4e38f; b2[rt][j] = 3.4e38f; i1[rt][j] = 0; }

    // 2-deep prologue, counted-vmcnt schedule; raw barriers (no vmcnt drain)
    stage(0, 0);
    stage(1, 1);
    for (int ct = 0; ct < 16; ++ct) {
        const int buf = ct & 1;
        if (ct < 15) {
            asm volatile("s_waitcnt vmcnt(8)" ::: "memory");   // tile ct landed; ct+1 in flight
        } else {
            asm volatile("s_waitcnt vmcnt(0)" ::: "memory");
        }
        __builtin_amdgcn_sched_barrier(0);
        __builtin_amdgcn_s_barrier();                          // all waves see tile ct

        const _Float16* wtb = wt[buf];
        f32x4 acc0[4], acc1[4];
#pragma unroll
        for (int cs = 0; cs < 4; ++cs) {
            acc0[cs] = (f32x4){0.f, 0.f, 0.f, 0.f};
            acc1[cs] = (f32x4){0.f, 0.f, 0.f, 0.f};
        }
#pragma unroll
        for (int ks = 0; ks < 8; ++ks) {
            const int kq = ks * 4 + g;
#pragma unroll
            for (int cs = 0; cs < 4; ++cs) {
                const int code = cs * 16 + m;
                const int L = code * 32 + (kq ^ (code & 31));
                f16x8 bh = *reinterpret_cast<const f16x8*>(wtb + L * 8);
                acc0[cs] = __builtin_amdgcn_mfma_f32_16x16x32_f16(ahr[0][ks], bh, acc0[cs], 0, 0, 0);
                acc1[cs] = __builtin_amdgcn_mfma_f32_16x16x32_f16(ahr[1][ks], bh, acc1[cs], 0, 0, 0);
            }
        }
#pragma unroll
        for (int cs = 0; cs < 4; ++cs) {
            const int code = ct * 64 + cs * 16 + m;
            const float sec = ses[code];
#pragma unroll
            for (int rt = 0; rt < 2; ++rt) {
                f32x4 A = rt ? acc1[cs] : acc0[cs];
#pragma unroll
                for (int j = 0; j < 4; ++j) {
                    float s = fmaf(-2.0f, A[j], sxr[rt][j] + sec);
                    if (s < b1[rt][j]) { b2[rt][j] = b1[rt][j]; b1[rt][j] = s; i1[rt][j] = code; }
                    else if (s < b2[rt][j]) { b2[rt][j] = s; }
                }
            }
        }
        __builtin_amdgcn_s_barrier();                          // all waves done reading buf
        if (ct < 14) stage(ct + 2, buf);                       // overwrite consumed buffer
    }

#pragma unroll
    for (int rt = 0; rt < 2; ++rt)
#pragma unroll
        for (int j = 0; j < 4; ++j) {
            float v1 = b1[rt][j], v2 = b2[rt][j];
            int ix = i1[rt][j];
            for (int mm = 1; mm < 16; mm <<= 1) {
                float ov1 = __shfl_xor(v1, mm, 64);
                int oi = __shfl_xor(ix, mm, 64);
                float ov2 = __shfl_xor(v2, mm, 64);
                float nv2 = fminf(fminf(v2, ov2), fmaxf(v1, ov1));
                if (ov1 < v1 || (ov1 == v1 && oi < ix)) { v1 = ov1; ix = oi; }
                v2 = nv2;
            }
            if (m == 0) {
                int rl = w * 32 + rt * 16 + g * 4 + j;
                argidx[rl] = ix;
                if (v2 - v1 < RESCUE_EPS) {
                    int p = atomicAdd(count, 1);
                    flags[p] = row0 + rl;
                }
            }
        }
    __syncthreads();

    if (tid < BM) {
        int row = row0 + tid;
        int k = argidx[tid];
        idx_int[row] = k;
        out_idx[row] = (float)k;
        sx_out[row] = sxs[tid];
        atomicAdd(&counts[k], 1.0f);
    }

    // register epilogue: out_q = (float)q; fp32 loss
    {
        float lacc = 0.0f;
#pragma unroll
        for (int rt = 0; rt < 2; ++rt) {
            const int rl = w * 32 + rt * 16 + m;
            const int row = row0 + rl;
            const int k = argidx[rl];
            const _Float16* qh = wh + (size_t)k * DD;
            float* orow = out_q + (size_t)row * DD;
#pragma unroll
            for (int ks = 0; ks < 8; ++ks) {
                const int col = ks * 32 + g * 8;
                union { uint4 u; _Float16 h[8]; } qv, xv;
                qv.u = *reinterpret_cast<const uint4*>(qh + col);
                xv.u = *reinterpret_cast<uint4*>(&ahr[rt][ks]);
                float o8[8];
#pragma unroll
                for (int q = 0; q < 8; ++q) {
                    float qf = (float)qv.h[q];
                    float df = qf - (float)xv.h[q];
                    o8[q] = qf;
                    lacc = fmaf(df, df, lacc);
                }
                *reinterpret_cast<float4*>(orow + col)     = *reinterpret_cast<float4*>(&o8[0]);
                *reinterpret_cast<float4*>(orow + col + 4) = *reinterpret_cast<float4*>(&o8[4]);
            }
        }
        for (int mm = 32; mm >= 1; mm >>= 1) lacc += __shfl_xor(lacc, mm, 64);
        if (lane == 0) lred[w] = (double)lacc;
    }
    __syncthreads();
    if (tid == 0) {
        double t = lred[0] + lred[1] + lred[2] + lred[3];
        atomicAdd(loss_acc, t);
    }
}

__global__ __launch_bounds__(256) void rescue(
    const float* __restrict__ X, const float4* __restrict__ WT4,
    const float* __restrict__ Wf,
    const float* __restrict__ se, const float* __restrict__ sx,
    const int* __restrict__ flags, const int* __restrict__ count,
    int* __restrict__ idx_int, float* __restrict__ out_idx,
    float* __restrict__ out_q, float* __restrict__ counts,
    double* __restrict__ loss_acc)
{
    __shared__ __align__(16) float xs[RB][DD];
    __shared__ float rv[RB][256];
    __shared__ int ri[RB][256];
    __shared__ float sxr_s[RB];
    __shared__ int rows_s[RB];
    __shared__ int kn_s[RB], ko_s[RB];
    __shared__ double dred[4];
    const int t = threadIdx.x;
    const int n = count[0];

    for (int base = blockIdx.x * RB; base < n; base += gridDim.x * RB) {
        const int nb = min(RB, n - base);
        for (int idx = t; idx < nb * 64; idx += 256) {
            int r = idx >> 6, c4 = idx & 63;
            float4 v = reinterpret_cast<const float4*>(X + (size_t)flags[base + r] * DD)[c4];
            *reinterpret_cast<float4*>(&xs[r][c4 * 4]) = v;
        }
        if (t < nb) { rows_s[t] = flags[base + t]; sxr_s[t] = sx[flags[base + t]]; }
        __syncthreads();

        float acc[4][RB];
#pragma unroll
        for (int cc = 0; cc < 4; ++cc)
#pragma unroll
            for (int r = 0; r < RB; ++r) acc[cc][r] = 0.0f;

        float4 wv[4], wn[4];
#pragma unroll
        for (int cc = 0; cc < 4; ++cc) wv[cc] = WT4[(size_t)0 * KC + cc * 256 + t];

        for (int d4 = 0; d4 < 64; ++d4) {
            const int dn = (d4 < 63) ? d4 + 1 : 63;
#pragma unroll
            for (int cc = 0; cc < 4; ++cc) wn[cc] = WT4[(size_t)dn * KC + cc * 256 + t];
#pragma unroll
            for (int r = 0; r < RB; ++r) {
                float4 xv = *reinterpret_cast<const float4*>(&xs[r][d4 * 4]);
#pragma unroll
                for (int cc = 0; cc < 4; ++cc)
                    acc[cc][r] = fmaf(xv.w, wv[cc].w, fmaf(xv.z, wv[cc].z,
                                 fmaf(xv.y, wv[cc].y, fmaf(xv.x, wv[cc].x, acc[cc][r]))));
            }
#pragma unroll
            for (int cc = 0; cc < 4; ++cc) wv[cc] = wn[cc];
        }

        float best[RB];
        int bidx[RB];
#pragma unroll
        for (int r = 0; r < RB; ++r) { best[r] = 3.4e38f; bidx[r] = 0; }
#pragma unroll
        for (int cc = 0; cc < 4; ++cc) {
            const int c = cc * 256 + t;
            const float sec = se[c];
#pragma unroll
            for (int r = 0; r < RB; ++r) {
                float s = __fsub_rn(__fadd_rn(sxr_s[r], sec), __fmul_rn(2.0f, acc[cc][r]));
                if (s < best[r] || (s == best[r] && c < bidx[r])) { best[r] = s; bidx[r] = c; }
            }
        }
#pragma unroll
        for (int r = 0; r < RB; ++r) { rv[r][t] = best[r]; ri[r][t] = bidx[r]; }
        __syncthreads();

        for (int sft = 128; sft >= 1; sft >>= 1) {
            if (t < sft) {
#pragma unroll
                for (int r = 0; r < RB; ++r) {
                    float ov = rv[r][t + sft];
                    int oi = ri[r][t + sft];
                    if (ov < rv[r][t] || (ov == rv[r][t] && oi < ri[r][t])) {
                        rv[r][t] = ov; ri[r][t] = oi;
                    }
                }
            }
            __syncthreads();
        }
        if (t < nb) {
            int row = rows_s[t];
            int kn = ri[t][0], ko = idx_int[row];
            kn_s[t] = kn; ko_s[t] = ko;
            if (kn != ko) {
                idx_int[row] = kn;
                out_idx[row] = (float)kn;
                atomicAdd(&counts[ko], -1.0f);
                atomicAdd(&counts[kn], 1.0f);
            }
        }
        __syncthreads();

        for (int r = 0; r < nb; ++r) {
            const int ko = ko_s[r], kn = kn_s[r];
            if (kn != ko) {
                const int row = rows_s[r];
                float x = xs[r][t];
                float qo = Wf[(size_t)ko * DD + t];
                float qn = Wf[(size_t)kn * DD + t];
                float dfn = qn - x, dfo = qo - x;
                out_q[(size_t)row * DD + t] = x + dfn;
                double dl = (double)dfn * dfn - (double)dfo * dfo;
                for (int mm = 32; mm >= 1; mm >>= 1) dl += __shfl_xor(dl, mm, 64);
                if ((t & 63) == 0) dred[t >> 6] = dl;
                __syncthreads();
                if (t == 0) atomicAdd(loss_acc, dred[0] + dred[1] + dred[2] + dred[3]);
                __syncthreads();
            }
        }
        __syncthreads();
    }
}

__global__ void finprefix(const float* __restrict__ ema_cs, float* __restrict__ ncs_buf,
                          const double* __restrict__ loss_acc, float* __restrict__ out_loss,
                          float* __restrict__ n_out, int* __restrict__ off,
                          int* __restrict__ cur)
{
    __shared__ float red[1024];
    __shared__ int s[1024];
    int t = threadIdx.x;
    const float OM = (float)(1.0 - 0.99);
    float cnt = ncs_buf[t];
    s[t] = (int)cnt;
    float ncs = __fadd_rn(__fmul_rn(0.99f, ema_cs[t]), __fmul_rn(OM, cnt));
    ncs_buf[t] = ncs;
    red[t] = ncs;
    __syncthreads();
    for (int st = 512; st >= 1; st >>= 1) {
        if (t < st) red[t] += red[t + st];
        __syncthreads();
    }
    if (t == 0) {
        n_out[0] = red[0];
        float el = (float)(loss_acc[0] / 16777216.0);
        out_loss[0] = __fadd_rn(el, __fmul_rn(0.25f, el));
    }
    for (int d = 1; d < 1024; d <<= 1) {
        int v = (t >= d) ? s[t - d] : 0;
        __syncthreads();
        s[t] += v;
        __syncthreads();
    }
    off[t] = (t == 0) ? 0 : s[t - 1];
    cur[t] = 0;
    if (t == 0) off[1024] = NROWS;
}

__global__ __launch_bounds__(256) void scatter_rows(
    const int* __restrict__ idx_int, const int* __restrict__ off,
    int* __restrict__ cur, int* __restrict__ sorted) {
    int i = blockIdx.x * 256 + threadIdx.x;
    int k = idx_int[i];
    int p = atomicAdd(&cur[k], 1);
    sorted[off[k] + p] = i;
}

__global__ __launch_bounds__(256) void embfin2(
    const float* __restrict__ X, const int* __restrict__ off,
    const int* __restrict__ sorted, const float* __restrict__ ema_avg,
    const float* __restrict__ ncs, const float* __restrict__ n_ptr,
    float* __restrict__ out_avg, float* __restrict__ out_w)
{
    const int k = blockIdx.x, t = threadIdx.x;
    const int s0 = off[k], s1 = off[k + 1];
    float a0 = 0.f, a1 = 0.f, a2 = 0.f, a3 = 0.f;
    int i = s0;
    for (; i + 4 <= s1; i += 4) {
        int r0 = sorted[i], r1 = sorted[i + 1], r2 = sorted[i + 2], r3 = sorted[i + 3];
        a0 += X[(size_t)r0 * DD + t];
        a1 += X[(size_t)r1 * DD + t];
        a2 += X[(size_t)r2 * DD + t];
        a3 += X[(size_t)r3 * DD + t];
    }
    for (; i < s1; ++i) a0 += X[(size_t)sorted[i] * DD + t];
    float total = (a0 + a1) + (a2 + a3);

    const float OM = (float)(1.0 - 0.99);
    const float KEPS = (float)(1024.0 * 1e-5);
    size_t o = (size_t)k * DD + t;
    float avg = __fadd_rn(__fmul_rn(0.99f, ema_avg[o]), __fmul_rn(OM, total));
    float n = n_ptr[0];
    float cs = __fmul_rn(__fdiv_rn(__fadd_rn(ncs[k], 1e-5f), __fadd_rn(n, KEPS)), n);
    out_avg[o] = avg;
    out_w[o] = __fdiv_rn(avg, cs);
}

extern "C" void kernel_launch(void* const* d_in, const int* in_sizes, int n_in,
                              void* d_out, int out_size, void* d_ws, size_t ws_size,
                              hipStream_t stream) {
    const float* X = (const float*)d_in[0];
    const float* W = (const float*)d_in[1];
    const float* ema_cs = (const float*)d_in[2];
    const float* ema_avg = (const float*)d_in[3];

    float* out = (float*)d_out;
    float* out_q    = out;
    float* out_loss = out + 16777216;
    float* out_idx  = out + 16777217;
    float* out_w    = out + 16842753;
    float* out_ncs  = out + 17104897;
    float* out_avg  = out + 17105921;

    char* ws = (char*)d_ws;
    float* se      = (float*)(ws + 0);
    float* n_ptr   = (float*)(ws + 4096);
    double* loss   = (double*)(ws + 4112);
    int*   count   = (int*)(ws + 4128);
    _Float16* wh   = (_Float16*)(ws + 8192);
    float* sx      = (float*)(ws + 1056768);
    int*   idx_int = (int*)(ws + 1318912);
    int*   flags   = (int*)(ws + 1581056);
    float4* WT4    = (float4*)(ws + 2097152);
    int*   off     = (int*)(ws + 3145728);
    int*   cur     = (int*)(ws + 3153920);
    int*   sorted  = (int*)(ws + 3158016);

    wprep<<<KC, 64, 0, stream>>>(W, wh, se, WT4, out_ncs, loss, count);
    vq_mfma<<<NROWS / BM, NT, 0, stream>>>(X, wh, se, out_q, out_idx,
                                           idx_int, sx, flags, count,
                                           out_ncs, loss);
    rescue<<<512, 256, 0, stream>>>(X, WT4, W, se, sx, flags, count, idx_int, out_idx,
                                    out_q, out_ncs, loss);
    finprefix<<<1, 1024, 0, stream>>>(ema_cs, out_ncs, loss, out_loss, n_ptr, off, cur);
    scatter_rows<<<NROWS / 256, 256, 0, stream>>>(idx_int, off, cur, sorted);
    embfin2<<<KC, 256, 0, stream>>>(X, off, sorted, ema_avg, out_ncs, n_ptr,
                                    out_avg, out_w);
}

// Round 30
// 173.056 us; speedup vs baseline: 1.5581x; 1.0199x over previous
//
#include <hip/hip_runtime.h>

#define KC 1024
#define DD 256
#define NROWS 65536
#define BM 128
#define NT 256
#define RESCUE_EPS 0.02f
#define RB 8

typedef _Float16 f16x8 __attribute__((ext_vector_type(8)));
typedef __fp16 fp16x2 __attribute__((ext_vector_type(2)));
typedef float f32x4 __attribute__((ext_vector_type(4)));
typedef const __attribute__((address_space(1))) unsigned int* gptr_t;
typedef __attribute__((address_space(3))) unsigned int* lptr_t;

__global__ void wprep(const float* __restrict__ W, _Float16* __restrict__ wh,
                      float* __restrict__ se, float4* __restrict__ WT4,
                      float* __restrict__ counts, double* __restrict__ loss,
                      int* __restrict__ flagcnt) {
    int k = blockIdx.x, lane = threadIdx.x;
    float4 v = reinterpret_cast<const float4*>(W + (size_t)k * DD)[lane];
    union { fp16x2 h2[2]; uint2 u; } cv;
    cv.h2[0] = __builtin_amdgcn_cvt_pkrtz(v.x, v.y);
    cv.h2[1] = __builtin_amdgcn_cvt_pkrtz(v.z, v.w);
    *reinterpret_cast<uint2*>(wh + (size_t)k * DD + lane * 4) = cv.u;
    WT4[(size_t)lane * KC + k] = v;
    double s = (double)v.x * v.x + (double)v.y * v.y + (double)v.z * v.z + (double)v.w * v.w;
    for (int m = 32; m >= 1; m >>= 1) s += __shfl_xor(s, m, 64);
    if (lane == 0) {
        se[k] = (float)s;
        counts[k] = 0.0f;
        if (k == 0) { loss[0] = 0.0; flagcnt[0] = 0; }
    }
}

__global__ __launch_bounds__(NT, 2) void vq_mfma(
    const float* __restrict__ X,
    const _Float16* __restrict__ wh,
    const float* __restrict__ se,
    float* __restrict__ out_q, float* __restrict__ out_idx,
    int* __restrict__ idx_int, float* __restrict__ sx_out,
    int* __restrict__ flags, int* __restrict__ count,
    float* __restrict__ counts, double* __restrict__ loss_acc)
{
    __shared__ __align__(16) _Float16 wt[2][64 * 256];  // 32 KB x2
    __shared__ float sxs[BM];
    __shared__ float ses[KC];
    __shared__ int argidx[BM];
    __shared__ double lred[4];

    const int tid = threadIdx.x;
    const int row0 = blockIdx.x * BM;
    const int w = tid >> 6, lane = tid & 63;   // 4 waves, wave owns rows w*32..w*32+31
    const int m = lane & 15, g = lane >> 4;

    for (int i = tid; i < KC; i += NT) ses[i] = se[i];

    f16x8 ahr[2][8];
#pragma unroll
    for (int rt = 0; rt < 2; ++rt) {
        const float* xr = X + (size_t)(row0 + w * 32 + rt * 16 + m) * DD;
        float p0 = 0.f, p1 = 0.f, p2 = 0.f, p3 = 0.f;
#pragma unroll
        for (int ks = 0; ks < 8; ++ks) {
            float4 a = *reinterpret_cast<const float4*>(xr + ks * 32 + g * 8);
            float4 b = *reinterpret_cast<const float4*>(xr + ks * 32 + g * 8 + 4);
            union { fp16x2 h2[4]; f16x8 h8; } cv;
            cv.h2[0] = __builtin_amdgcn_cvt_pkrtz(a.x, a.y);
            cv.h2[1] = __builtin_amdgcn_cvt_pkrtz(a.z, a.w);
            cv.h2[2] = __builtin_amdgcn_cvt_pkrtz(b.x, b.y);
            cv.h2[3] = __builtin_amdgcn_cvt_pkrtz(b.z, b.w);
            ahr[rt][ks] = cv.h8;
            p0 = fmaf(a.x, a.x, fmaf(b.x, b.x, p0));
            p1 = fmaf(a.y, a.y, fmaf(b.y, b.y, p1));
            p2 = fmaf(a.z, a.z, fmaf(b.z, b.z, p2));
            p3 = fmaf(a.w, a.w, fmaf(b.w, b.w, p3));
        }
        float ss = (p0 + p1) + (p2 + p3);
        ss += __shfl_xor(ss, 16, 64);
        ss += __shfl_xor(ss, 32, 64);
        if (g == 0) sxs[w * 32 + rt * 16 + m] = ss;
    }
    __syncthreads();

    float sxr[2][4];
#pragma unroll
    for (int rt = 0; rt < 2; ++rt)
#pragma unroll
        for (int j = 0; j < 4; ++j) sxr[rt][j] = sxs[w * 32 + rt * 16 + g * 4 + j];

    unsigned srcoff[8], ldsoff[8];
#pragma unroll
    for (int p = 0; p < 8; ++p) {
        int gi = p * NT + tid;
        int code = gi >> 5, j = gi & 31;
        int kq = j ^ (code & 31);
        srcoff[p] = (unsigned)(code * DD + kq * 8);
        ldsoff[p] = gi * 8;
    }
    auto stage = [&](int ct, int buf) {
        const _Float16* b = wh + (size_t)ct * 64 * DD;
#pragma unroll
        for (int p = 0; p < 8; ++p)
            __builtin_amdgcn_global_load_lds((gptr_t)(const void*)(b + srcoff[p]),
                                             (lptr_t)(void*)&wt[buf][ldsoff[p]], 16, 0, 0);
    };

    float b1[2][4], b2[2][4];
    int i1[2][4];
#pragma unroll
    for (int rt = 0; rt < 2; ++rt)
#pragma unroll
        for (int j = 0; j < 4; ++j) { b1[rt][j] = 3.4e38f; b2[rt][j] = 3.4e38f; i1[rt][j] = 0; }

    stage(0, 0);
    stage(1, 1);
    for (int ct = 0; ct < 16; ++ct) {
        const int buf = ct & 1;
        if (ct < 15) {
            asm volatile("s_waitcnt vmcnt(8)" ::: "memory");
        } else {
            asm volatile("s_waitcnt vmcnt(0)" ::: "memory");
        }
        __builtin_amdgcn_sched_barrier(0);
        __builtin_amdgcn_s_barrier();

        const _Float16* wtb = wt[buf];
        f32x4 acc0[4], acc1[4];
#pragma unroll
        for (int cs = 0; cs < 4; ++cs) {
            acc0[cs] = (f32x4){0.f, 0.f, 0.f, 0.f};
            acc1[cs] = (f32x4){0.f, 0.f, 0.f, 0.f};
        }
        __builtin_amdgcn_s_setprio(1);
#pragma unroll
        for (int ks = 0; ks < 8; ++ks) {
            const int kq = ks * 4 + g;
#pragma unroll
            for (int cs = 0; cs < 4; ++cs) {
                const int code = cs * 16 + m;
                const int L = code * 32 + (kq ^ (code & 31));
                f16x8 bh = *reinterpret_cast<const f16x8*>(wtb + L * 8);
                acc0[cs] = __builtin_amdgcn_mfma_f32_16x16x32_f16(ahr[0][ks], bh, acc0[cs], 0, 0, 0);
                acc1[cs] = __builtin_amdgcn_mfma_f32_16x16x32_f16(ahr[1][ks], bh, acc1[cs], 0, 0, 0);
            }
        }
        __builtin_amdgcn_s_setprio(0);
#pragma unroll
        for (int cs = 0; cs < 4; ++cs) {
            const int code = ct * 64 + cs * 16 + m;
            const float sec = ses[code];
#pragma unroll
            for (int rt = 0; rt < 2; ++rt) {
                f32x4 A = rt ? acc1[cs] : acc0[cs];
#pragma unroll
                for (int j = 0; j < 4; ++j) {
                    float s = fmaf(-2.0f, A[j], sxr[rt][j] + sec);
                    if (s < b1[rt][j]) { b2[rt][j] = b1[rt][j]; b1[rt][j] = s; i1[rt][j] = code; }
                    else if (s < b2[rt][j]) { b2[rt][j] = s; }
                }
            }
        }
        __builtin_amdgcn_s_barrier();
        if (ct < 14) stage(ct + 2, buf);
    }

#pragma unroll
    for (int rt = 0; rt < 2; ++rt)
#pragma unroll
        for (int j = 0; j < 4; ++j) {
            float v1 = b1[rt][j], v2 = b2[rt][j];
            int ix = i1[rt][j];
            for (int mm = 1; mm < 16; mm <<= 1) {
                float ov1 = __shfl_xor(v1, mm, 64);
                int oi = __shfl_xor(ix, mm, 64);
                float ov2 = __shfl_xor(v2, mm, 64);
                float nv2 = fminf(fminf(v2, ov2), fmaxf(v1, ov1));
                if (ov1 < v1 || (ov1 == v1 && oi < ix)) { v1 = ov1; ix = oi; }
                v2 = nv2;
            }
            if (m == 0) {
                int rl = w * 32 + rt * 16 + g * 4 + j;
                argidx[rl] = ix;
                if (v2 - v1 < RESCUE_EPS) {
                    int p = atomicAdd(count, 1);
                    flags[p] = row0 + rl;
                }
            }
        }
    __syncthreads();

    if (tid < BM) {
        int row = row0 + tid;
        int k = argidx[tid];
        idx_int[row] = k;
        out_idx[row] = (float)k;
        sx_out[row] = sxs[tid];
        atomicAdd(&counts[k], 1.0f);
    }

    {
        float lacc = 0.0f;
#pragma unroll
        for (int rt = 0; rt < 2; ++rt) {
            const int rl = w * 32 + rt * 16 + m;
            const int row = row0 + rl;
            const int k = argidx[rl];
            const _Float16* qh = wh + (size_t)k * DD;
            float* orow = out_q + (size_t)row * DD;
#pragma unroll
            for (int ks = 0; ks < 8; ++ks) {
                const int col = ks * 32 + g * 8;
                union { uint4 u; _Float16 h[8]; } qv, xv;
                qv.u = *reinterpret_cast<const uint4*>(qh + col);
                xv.u = *reinterpret_cast<uint4*>(&ahr[rt][ks]);
                float o8[8];
#pragma unroll
                for (int q = 0; q < 8; ++q) {
                    float qf = (float)qv.h[q];
                    float df = qf - (float)xv.h[q];
                    o8[q] = qf;
                    lacc = fmaf(df, df, lacc);
                }
                *reinterpret_cast<float4*>(orow + col)     = *reinterpret_cast<float4*>(&o8[0]);
                *reinterpret_cast<float4*>(orow + col + 4) = *reinterpret_cast<float4*>(&o8[4]);
            }
        }
        for (int mm = 32; mm >= 1; mm >>= 1) lacc += __shfl_xor(lacc, mm, 64);
        if (lane == 0) lred[w] = (double)lacc;
    }
    __syncthreads();
    if (tid == 0) {
        double t = lred[0] + lred[1] + lred[2] + lred[3];
        atomicAdd(loss_acc, t);
    }
}

__global__ __launch_bounds__(256) void rescue(
    const float* __restrict__ X, const float4* __restrict__ WT4,
    const float* __restrict__ Wf,
    const float* __restrict__ se, const float* __restrict__ sx,
    const int* __restrict__ flags, const int* __restrict__ count,
    int* __restrict__ idx_int, float* __restrict__ out_idx,
    float* __restrict__ out_q, float* __restrict__ counts,
    double* __restrict__ loss_acc)
{
    __shared__ __align__(16) float xs[RB][DD];
    __shared__ float rv[RB][256];
    __shared__ int ri[RB][256];
    __shared__ float sxr_s[RB];
    __shared__ int rows_s[RB];
    __shared__ int kn_s[RB], ko_s[RB];
    __shared__ double dred[4];
    const int t = threadIdx.x;
    const int n = count[0];

    for (int base = blockIdx.x * RB; base < n; base += gridDim.x * RB) {
        const int nb = min(RB, n - base);
        for (int idx = t; idx < nb * 64; idx += 256) {
            int r = idx >> 6, c4 = idx & 63;
            float4 v = reinterpret_cast<const float4*>(X + (size_t)flags[base + r] * DD)[c4];
            *reinterpret_cast<float4*>(&xs[r][c4 * 4]) = v;
        }
        if (t < nb) { rows_s[t] = flags[base + t]; sxr_s[t] = sx[flags[base + t]]; }
        __syncthreads();

        float acc[4][RB];
#pragma unroll
        for (int cc = 0; cc < 4; ++cc)
#pragma unroll
            for (int r = 0; r < RB; ++r) acc[cc][r] = 0.0f;

        float4 wv[4], wn[4];
#pragma unroll
        for (int cc = 0; cc < 4; ++cc) wv[cc] = WT4[(size_t)0 * KC + cc * 256 + t];

        for (int d4 = 0; d4 < 64; ++d4) {
            const int dn = (d4 < 63) ? d4 + 1 : 63;
#pragma unroll
            for (int cc = 0; cc < 4; ++cc) wn[cc] = WT4[(size_t)dn * KC + cc * 256 + t];
#pragma unroll
            for (int r = 0; r < RB; ++r) {
                float4 xv = *reinterpret_cast<const float4*>(&xs[r][d4 * 4]);
#pragma unroll
                for (int cc = 0; cc < 4; ++cc)
                    acc[cc][r] = fmaf(xv.w, wv[cc].w, fmaf(xv.z, wv[cc].z,
                                 fmaf(xv.y, wv[cc].y, fmaf(xv.x, wv[cc].x, acc[cc][r]))));
            }
#pragma unroll
            for (int cc = 0; cc < 4; ++cc) wv[cc] = wn[cc];
        }

        float best[RB];
        int bidx[RB];
#pragma unroll
        for (int r = 0; r < RB; ++r) { best[r] = 3.4e38f; bidx[r] = 0; }
#pragma unroll
        for (int cc = 0; cc < 4; ++cc) {
            const int c = cc * 256 + t;
            const float sec = se[c];
#pragma unroll
            for (int r = 0; r < RB; ++r) {
                float s = __fsub_rn(__fadd_rn(sxr_s[r], sec), __fmul_rn(2.0f, acc[cc][r]));
                if (s < best[r] || (s == best[r] && c < bidx[r])) { best[r] = s; bidx[r] = c; }
            }
        }
#pragma unroll
        for (int r = 0; r < RB; ++r) { rv[r][t] = best[r]; ri[r][t] = bidx[r]; }
        __syncthreads();

        for (int sft = 128; sft >= 1; sft >>= 1) {
            if (t < sft) {
#pragma unroll
                for (int r = 0; r < RB; ++r) {
                    float ov = rv[r][t + sft];
                    int oi = ri[r][t + sft];
                    if (ov < rv[r][t] || (ov == rv[r][t] && oi < ri[r][t])) {
                        rv[r][t] = ov; ri[r][t] = oi;
                    }
                }
            }
            __syncthreads();
        }
        if (t < nb) {
            int row = rows_s[t];
            int kn = ri[t][0], ko = idx_int[row];
            kn_s[t] = kn; ko_s[t] = ko;
            if (kn != ko) {
                idx_int[row] = kn;
                out_idx[row] = (float)kn;
                atomicAdd(&counts[ko], -1.0f);
                atomicAdd(&counts[kn], 1.0f);
            }
        }
        __syncthreads();

        for (int r = 0; r < nb; ++r) {
            const int ko = ko_s[r], kn = kn_s[r];
            if (kn != ko) {
                const int row = rows_s[r];
                float x = xs[r][t];
                float qo = Wf[(size_t)ko * DD + t];
                float qn = Wf[(size_t)kn * DD + t];
                float dfn = qn - x, dfo = qo - x;
                out_q[(size_t)row * DD + t] = x + dfn;
                double dl = (double)dfn * dfn - (double)dfo * dfo;
                for (int mm = 32; mm >= 1; mm >>= 1) dl += __shfl_xor(dl, mm, 64);
                if ((t & 63) == 0) dred[t >> 6] = dl;
                __syncthreads();
                if (t == 0) atomicAdd(loss_acc, dred[0] + dred[1] + dred[2] + dred[3]);
                __syncthreads();
            }
        }
        __syncthreads();
    }
}

__global__ void finprefix(const float* __restrict__ ema_cs, float* __restrict__ ncs_buf,
                          const double* __restrict__ loss_acc, float* __restrict__ out_loss,
                          float* __restrict__ n_out, int* __restrict__ off,
                          int* __restrict__ cur)
{
    __shared__ float red[1024];
    __shared__ int s[1024];
    int t = threadIdx.x;
    const float OM = (float)(1.0 - 0.99);
    float cnt = ncs_buf[t];
    s[t] = (int)cnt;
    float ncs = __fadd_rn(__fmul_rn(0.99f, ema_cs[t]), __fmul_rn(OM, cnt));
    ncs_buf[t] = ncs;
    red[t] = ncs;
    __syncthreads();
    for (int st = 512; st >= 1; st >>= 1) {
        if (t < st) red[t] += red[t + st];
        __syncthreads();
    }
    if (t == 0) {
        n_out[0] = red[0];
        float el = (float)(loss_acc[0] / 16777216.0);
        out_loss[0] = __fadd_rn(el, __fmul_rn(0.25f, el));
    }
    for (int d = 1; d < 1024; d <<= 1) {
        int v = (t >= d) ? s[t - d] : 0;
        __syncthreads();
        s[t] += v;
        __syncthreads();
    }
    off[t] = (t == 0) ? 0 : s[t - 1];
    cur[t] = 0;
    if (t == 0) off[1024] = NROWS;
}

__global__ __launch_bounds__(256) void scatter_rows(
    const int* __restrict__ idx_int, const int* __restrict__ off,
    int* __restrict__ cur, int* __restrict__ sorted) {
    int i = blockIdx.x * 256 + threadIdx.x;
    int k = idx_int[i];
    int p = atomicAdd(&cur[k], 1);
    sorted[off[k] + p] = i;
}

__global__ __launch_bounds__(256) void embfin2(
    const float* __restrict__ X, const int* __restrict__ off,
    const int* __restrict__ sorted, const float* __restrict__ ema_avg,
    const float* __restrict__ ncs, const float* __restrict__ n_ptr,
    float* __restrict__ out_avg, float* __restrict__ out_w)
{
    const int k = blockIdx.x, t = threadIdx.x;
    const int s0 = off[k], s1 = off[k + 1];
    float a0 = 0.f, a1 = 0.f, a2 = 0.f, a3 = 0.f;
    int i = s0;
    for (; i + 4 <= s1; i += 4) {
        int r0 = sorted[i], r1 = sorted[i + 1], r2 = sorted[i + 2], r3 = sorted[i + 3];
        a0 += X[(size_t)r0 * DD + t];
        a1 += X[(size_t)r1 * DD + t];
        a2 += X[(size_t)r2 * DD + t];
        a3 += X[(size_t)r3 * DD + t];
    }
    for (; i < s1; ++i) a0 += X[(size_t)sorted[i] * DD + t];
    float total = (a0 + a1) + (a2 + a3);

    const float OM = (float)(1.0 - 0.99);
    const float KEPS = (float)(1024.0 * 1e-5);
    size_t o = (size_t)k * DD + t;
    float avg = __fadd_rn(__fmul_rn(0.99f, ema_avg[o]), __fmul_rn(OM, total));
    float n = n_ptr[0];
    float cs = __fmul_rn(__fdiv_rn(__fadd_rn(ncs[k], 1e-5f), __fadd_rn(n, KEPS)), n);
    out_avg[o] = avg;
    out_w[o] = __fdiv_rn(avg, cs);
}

extern "C" void kernel_launch(void* const* d_in, const int* in_sizes, int n_in,
                              void* d_out, int out_size, void* d_ws, size_t ws_size,
                              hipStream_t stream) {
    const float* X = (const float*)d_in[0];
    const float* W = (const float*)d_in[1];
    const float* ema_cs = (const float*)d_in[2];
    const float* ema_avg = (const float*)d_in[3];

    float* out = (float*)d_out;
    float* out_q    = out;
    float* out_loss = out + 16777216;
    float* out_idx  = out + 16777217;
    float* out_w    = out + 16842753;
    float* out_ncs  = out + 17104897;
    float* out_avg  = out + 17105921;

    char* ws = (char*)d_ws;
    float* se      = (float*)(ws + 0);
    float* n_ptr   = (float*)(ws + 4096);
    double* loss   = (double*)(ws + 4112);
    int*   count   = (int*)(ws + 4128);
    _Float16* wh   = (_Float16*)(ws + 8192);
    float* sx      = (float*)(ws + 1056768);
    int*   idx_int = (int*)(ws + 1318912);
    int*   flags   = (int*)(ws + 1581056);
    float4* WT4    = (float4*)(ws + 2097152);
    int*   off     = (int*)(ws + 3145728);
    int*   cur     = (int*)(ws + 3153920);
    int*   sorted  = (int*)(ws + 3158016);

    wprep<<<KC, 64, 0, stream>>>(W, wh, se, WT4, out_ncs, loss, count);
    vq_mfma<<<NROWS / BM, NT, 0, stream>>>(X, wh, se, out_q, out_idx,
                                           idx_int, sx, flags, count,
                                           out_ncs, loss);
    rescue<<<512, 256, 0, stream>>>(X, WT4, W, se, sx, flags, count, idx_int, out_idx,
                                    out_q, out_ncs, loss);
    finprefix<<<1, 1024, 0, stream>>>(ema_cs, out_ncs, loss, out_loss, n_ptr, off, cur);
    scatter_rows<<<NROWS / 256, 256, 0, stream>>>(idx_int, off, cur, sorted);
    embfin2<<<KC, 256, 0, stream>>>(X, off, sorted, ema_avg, out_ncs, n_ptr,
                                    out_avg, out_w);
}